// Round 1
// baseline (656.895 us; speedup 1.0000x reference)
//
#include <hip/hip_runtime.h>
#include <hip/hip_bf16.h>
#include <math.h>

#define B_  32
#define T_  2048
#define H_  1024
#define LD_ 1024
#define M_  (B_*T_)   // 65536 rows of enc

typedef __attribute__((ext_vector_type(8))) short bf16x8;
typedef __attribute__((ext_vector_type(4))) float f32x4;

__device__ __forceinline__ void async_copy16(void* lds, const void* g) {
  __builtin_amdgcn_global_load_lds(
      (const __attribute__((address_space(1))) void*)g,
      (__attribute__((address_space(3))) void*)lds, 16, 0, 0);
}

// W2 [H, LD] fp32 -> w2p bf16 in k-grouped layout: w2p[(k/8)*LD*8 + n*8 + (k%8)]
__global__ void convert_w2(const float* __restrict__ W2, __hip_bfloat16* __restrict__ w2p) {
  int idx = blockIdx.x * 256 + threadIdx.x;        // 1M elements
  int k = idx >> 10, n = idx & 1023;
  w2p[((size_t)(k >> 3)) * (LD_ * 8) + n * 8 + (k & 7)] = __float2bfloat16(W2[idx]);
}

// dec_w[b][l] = sum_h dec[b][h] * W1[h][l] + b1[l]
__global__ void dec_proj(const float* __restrict__ dec, const float* __restrict__ W1,
                         const float* __restrict__ b1, float* __restrict__ dec_w) {
  __shared__ float sdec[H_];
  int bb = blockIdx.x >> 2;
  int l = (blockIdx.x & 3) * 256 + threadIdx.x;
  for (int i = threadIdx.x; i < H_; i += 256) sdec[i] = dec[bb * H_ + i];
  __syncthreads();
  float a0 = 0.f, a1 = 0.f, a2 = 0.f, a3 = 0.f;
  for (int h = 0; h < H_; h += 4) {
    a0 += sdec[h + 0] * W1[(h + 0) * LD_ + l];
    a1 += sdec[h + 1] * W1[(h + 1) * LD_ + l];
    a2 += sdec[h + 2] * W1[(h + 2) * LD_ + l];
    a3 += sdec[h + 3] * W1[(h + 3) * LD_ + l];
  }
  dec_w[bb * LD_ + l] = (a0 + a1) + (a2 + a3) + b1[l];
}

// Fused: enc_w tile via bf16 MFMA, then score[m] += sum_n tanh(dec_w[b,n]*(enc_w+b2[n]))*V[n]
__global__ void score_gemm(const float* __restrict__ enc,
                           const __hip_bfloat16* __restrict__ w2p,
                           const float* __restrict__ dec_w,
                           const float* __restrict__ b2,
                           const float* __restrict__ V,
                           float* __restrict__ score) {
  __shared__ __align__(16) __hip_bfloat16 Asm[4][128][8];  // [kg][m][k%8], 8KB
  __shared__ __align__(16) __hip_bfloat16 Bsm[4][128][8];  // [kg][n][k%8], 8KB

  const int tid  = threadIdx.x;
  const int lane = tid & 63;
  const int wave = tid >> 6;
  const int wm = wave >> 1, wn = wave & 1;       // 2x2 wave grid, 64x64 per wave
  const int nb = blockIdx.x, mb = blockIdx.y;
  const int row0 = mb * 128, col0 = nb * 128;
  const int q = lane >> 4, c15 = lane & 15;

  f32x4 acc[4][4] = {};

  const int sm  = tid >> 2;   // staging row within half-tile
  const int skg = tid & 3;    // staging k-group

  for (int k0 = 0; k0 < H_; k0 += 32) {
    // --- stage A: 128x32 fp32 -> bf16 ---
#pragma unroll
    for (int pass = 0; pass < 2; ++pass) {
      int m = pass * 64 + sm;
      const float4* src = reinterpret_cast<const float4*>(
          enc + (size_t)(row0 + m) * H_ + k0 + skg * 8);
      float4 f0 = src[0], f1 = src[1];
      __align__(16) __hip_bfloat16 h[8];
      h[0] = __float2bfloat16(f0.x); h[1] = __float2bfloat16(f0.y);
      h[2] = __float2bfloat16(f0.z); h[3] = __float2bfloat16(f0.w);
      h[4] = __float2bfloat16(f1.x); h[5] = __float2bfloat16(f1.y);
      h[6] = __float2bfloat16(f1.z); h[7] = __float2bfloat16(f1.w);
      *reinterpret_cast<uint4*>(&Asm[skg][m][0]) = *reinterpret_cast<const uint4*>(h);
    }
    // --- stage B: async global->LDS, already bf16 + pre-swizzled ---
    {
      char* bbase = (char*)&Bsm[0][0][0];
#pragma unroll
      for (int pass = 0; pass < 2; ++pass) {
        int o   = (wave + pass * 4) * 1024 + lane * 16;  // LDS byte offset
        int kg  = o >> 11;
        int rem = o & 2047;
        const char* g = (const char*)w2p
            + ((size_t)(k0 >> 3) + kg) * (size_t)(LD_ * 8 * 2)
            + (size_t)col0 * 16 + rem;
        async_copy16(bbase + o, g);
      }
    }
    __syncthreads();

    bf16x8 af[4], bfr[4];
#pragma unroll
    for (int i = 0; i < 4; ++i)
      af[i] = *reinterpret_cast<const bf16x8*>(&Asm[q][wm * 64 + i * 16 + c15][0]);
#pragma unroll
    for (int j = 0; j < 4; ++j)
      bfr[j] = *reinterpret_cast<const bf16x8*>(&Bsm[q][wn * 64 + j * 16 + c15][0]);
#pragma unroll
    for (int i = 0; i < 4; ++i)
#pragma unroll
      for (int j = 0; j < 4; ++j)
        acc[i][j] = __builtin_amdgcn_mfma_f32_16x16x32_bf16(af[i], bfr[j], acc[i][j], 0, 0, 0);
    __syncthreads();
  }

  // --- fused epilogue: tanh + V-dot + row reduction ---
  const int bb = row0 >> 11;   // batch index (2048 % 128 == 0, no straddle)
  float b2v[4], dwv[4], Vv[4];
#pragma unroll
  for (int j = 0; j < 4; ++j) {
    int n = col0 + wn * 64 + j * 16 + c15;
    b2v[j] = b2[n];
    dwv[j] = dec_w[bb * LD_ + n];
    Vv[j]  = V[n];
  }
#pragma unroll
  for (int i = 0; i < 4; ++i) {
#pragma unroll
    for (int r = 0; r < 4; ++r) {
      float v = 0.f;
#pragma unroll
      for (int j = 0; j < 4; ++j) {
        float e = acc[i][j][r] + b2v[j];          // enc_w + b2  (row=q*4+r, col=c15)
        v += tanhf(dwv[j] * e) * Vv[j];
      }
      v += __shfl_xor(v, 1);
      v += __shfl_xor(v, 2);
      v += __shfl_xor(v, 4);
      v += __shfl_xor(v, 8);                      // sum 16 cols within quad
      if (c15 == 0) {
        int row = row0 + wm * 64 + i * 16 + q * 4 + r;
        atomicAdd(&score[row], v);
      }
    }
  }
}

// softmax over T per batch; bV is softmax-invariant (scalar), omitted
__global__ void softmax_k(const float* __restrict__ score, float* __restrict__ attn) {
  int bb = blockIdx.x;
  int tid = threadIdx.x;
  int lane = tid & 63, wave = tid >> 6;
  __shared__ float red[4];
  float v[8];
  float mx = -3.4e38f;
#pragma unroll
  for (int i = 0; i < 8; ++i) {
    v[i] = score[bb * T_ + i * 256 + tid];
    mx = fmaxf(mx, v[i]);
  }
#pragma unroll
  for (int m = 32; m >= 1; m >>= 1) mx = fmaxf(mx, __shfl_xor(mx, m));
  if (lane == 0) red[wave] = mx;
  __syncthreads();
  mx = fmaxf(fmaxf(red[0], red[1]), fmaxf(red[2], red[3]));
  __syncthreads();
  float s = 0.f;
#pragma unroll
  for (int i = 0; i < 8; ++i) { v[i] = __expf(v[i] - mx); s += v[i]; }
#pragma unroll
  for (int m = 32; m >= 1; m >>= 1) s += __shfl_xor(s, m);
  if (lane == 0) red[wave] = s;
  __syncthreads();
  s = red[0] + red[1] + red[2] + red[3];
  float inv = 1.f / s;
#pragma unroll
  for (int i = 0; i < 8; ++i) attn[bb * T_ + i * 256 + tid] = v[i] * inv;
}

// context[b][h] = sum_t attn[b][t] * enc[b][t][h]; t split 4-way with atomics
__global__ void context_k(const float* __restrict__ enc, const float* __restrict__ attn,
                          float* __restrict__ ctx) {
  int bb = blockIdx.y;
  int hc = blockIdx.x & 3, tc = blockIdx.x >> 2;   // gridDim.x = 16
  int h = hc * 256 + threadIdx.x;
  __shared__ float sat[512];
  int t0 = tc * 512;
  for (int i = threadIdx.x; i < 512; i += 256) sat[i] = attn[bb * T_ + t0 + i];
  __syncthreads();
  const float* base = enc + ((size_t)bb * T_ + t0) * H_ + h;
  float a0 = 0.f, a1 = 0.f, a2 = 0.f, a3 = 0.f;
  for (int t = 0; t < 512; t += 4) {
    a0 += sat[t + 0] * base[(size_t)(t + 0) * H_];
    a1 += sat[t + 1] * base[(size_t)(t + 1) * H_];
    a2 += sat[t + 2] * base[(size_t)(t + 2) * H_];
    a3 += sat[t + 3] * base[(size_t)(t + 3) * H_];
  }
  atomicAdd(&ctx[bb * H_ + h], (a0 + a1) + (a2 + a3));
}

extern "C" void kernel_launch(void* const* d_in, const int* in_sizes, int n_in,
                              void* d_out, int out_size, void* d_ws, size_t ws_size,
                              hipStream_t stream) {
  const float* enc = (const float*)d_in[0];
  const float* dec = (const float*)d_in[1];
  const float* W1  = (const float*)d_in[2];
  const float* b1  = (const float*)d_in[3];
  const float* W2  = (const float*)d_in[4];
  const float* b2  = (const float*)d_in[5];
  const float* V   = (const float*)d_in[6];
  // d_in[7] = bV: softmax-invariant additive scalar -> ignored.

  char* ws = (char*)d_ws;
  __hip_bfloat16* w2p = (__hip_bfloat16*)ws;                       // 2 MB
  float* dec_w = (float*)(ws + (2u << 20));                        // 128 KB
  float* score = (float*)(ws + (2u << 20) + (128u << 10));         // 256 KB

  float* out  = (float*)d_out;
  float* ctx  = out;              // [B, H]   = 32768 floats
  float* attn = out + B_ * H_;    // [B, T, 1] = 65536 floats

  hipMemsetAsync(score, 0, (size_t)M_ * sizeof(float), stream);
  hipMemsetAsync(ctx, 0, (size_t)B_ * H_ * sizeof(float), stream);

  convert_w2<<<(H_ * LD_) / 256, 256, 0, stream>>>(W2, w2p);
  dec_proj<<<B_ * 4, 256, 0, stream>>>(dec, W1, b1, dec_w);
  score_gemm<<<dim3(LD_ / 128, M_ / 128), 256, 0, stream>>>(enc, w2p, dec_w, b2, V, score);
  softmax_k<<<B_, 256, 0, stream>>>(score, attn);
  context_k<<<dim3(16, B_), 256, 0, stream>>>(enc, attn, ctx);
}

// Round 2
// 643.100 us; speedup vs baseline: 1.0215x; 1.0215x over previous
//
#include <hip/hip_runtime.h>
#include <hip/hip_bf16.h>
#include <math.h>

#define B_  32
#define T_  2048
#define H_  1024
#define LD_ 1024
#define M_  (B_*T_)   // 65536 rows of enc

typedef __attribute__((ext_vector_type(8))) short bf16x8;
typedef __attribute__((ext_vector_type(4))) float f32x4;

__device__ __forceinline__ void async_copy16(void* lds, const void* g) {
  __builtin_amdgcn_global_load_lds(
      (const __attribute__((address_space(1))) void*)g,
      (__attribute__((address_space(3))) void*)lds, 16, 0, 0);
}

// W2 [H, LD] fp32 -> w2p bf16 k-grouped: w2p[(k/8)*LD*8 + n*8 + (k%8)]
// One thread per (kg, n): 8 coalesced reads, one 16B contiguous write.
__global__ void convert_w2(const float* __restrict__ W2, __hip_bfloat16* __restrict__ w2p) {
  int idx = blockIdx.x * 256 + threadIdx.x;        // 128K threads
  int kg = idx >> 10, n = idx & 1023;
  __align__(16) __hip_bfloat16 h[8];
#pragma unroll
  for (int j = 0; j < 8; ++j)
    h[j] = __float2bfloat16(W2[(size_t)(kg * 8 + j) * LD_ + n]);
  *reinterpret_cast<uint4*>(&w2p[(size_t)kg * (LD_ * 8) + n * 8]) =
      *reinterpret_cast<const uint4*>(h);
}

// dec_w[b][l] = sum_h dec[b][h] * W1[h][l] + b1[l]
__global__ void dec_proj(const float* __restrict__ dec, const float* __restrict__ W1,
                         const float* __restrict__ b1, float* __restrict__ dec_w) {
  __shared__ float sdec[H_];
  int bb = blockIdx.x >> 2;
  int l = (blockIdx.x & 3) * 256 + threadIdx.x;
  for (int i = threadIdx.x; i < H_; i += 256) sdec[i] = dec[bb * H_ + i];
  __syncthreads();
  float a0 = 0.f, a1 = 0.f, a2 = 0.f, a3 = 0.f;
  for (int h = 0; h < H_; h += 4) {
    a0 += sdec[h + 0] * W1[(h + 0) * LD_ + l];
    a1 += sdec[h + 1] * W1[(h + 1) * LD_ + l];
    a2 += sdec[h + 2] * W1[(h + 2) * LD_ + l];
    a3 += sdec[h + 3] * W1[(h + 3) * LD_ + l];
  }
  dec_w[bb * LD_ + l] = (a0 + a1) + (a2 + a3) + b1[l];
}

// Fused: enc_w tile via bf16 MFMA, then score[m] += sum_n tanh(dec_w[b,n]*(enc_w+b2[n]))*V[n]
// Tile: 128(M) x 256(N), BK=32, 4 waves in 2x2, wave tile 64x128 = acc[4][8].
__global__ __launch_bounds__(256, 2)
void score_gemm(const float* __restrict__ enc,
                const __hip_bfloat16* __restrict__ w2p,
                const float* __restrict__ dec_w,
                const float* __restrict__ b2,
                const float* __restrict__ V,
                float* __restrict__ score) {
  __shared__ __align__(16) __hip_bfloat16 Asm[4][128][8];  // [kg][m][k%8], 8KB
  __shared__ __align__(16) __hip_bfloat16 Bsm[4][256][8];  // [kg][n][k%8], 16KB

  const int tid  = threadIdx.x;
  const int lane = tid & 63;
  const int wave = tid >> 6;
  const int wm = wave >> 1, wn = wave & 1;       // 2x2 wave grid
  const int nb = blockIdx.x, mb = blockIdx.y;    // x-major: 4 nb of same mb adjacent (L3)
  const int row0 = mb * 128, col0 = nb * 256;
  const int q = lane >> 4, c15 = lane & 15;

  f32x4 acc[4][8] = {};

  const int sm  = tid >> 2;   // staging row within half-tile
  const int skg = tid & 3;    // staging k-group

  for (int k0 = 0; k0 < H_; k0 += 32) {
    // --- stage A: 128x32 fp32 -> bf16 (coalesced 128B/4-lane reads) ---
#pragma unroll
    for (int pass = 0; pass < 2; ++pass) {
      int m = pass * 64 + sm;
      const float4* src = reinterpret_cast<const float4*>(
          enc + (size_t)(row0 + m) * H_ + k0 + skg * 8);
      float4 f0 = src[0], f1 = src[1];
      __align__(16) __hip_bfloat16 h[8];
      h[0] = __float2bfloat16(f0.x); h[1] = __float2bfloat16(f0.y);
      h[2] = __float2bfloat16(f0.z); h[3] = __float2bfloat16(f0.w);
      h[4] = __float2bfloat16(f1.x); h[5] = __float2bfloat16(f1.y);
      h[6] = __float2bfloat16(f1.z); h[7] = __float2bfloat16(f1.w);
      *reinterpret_cast<uint4*>(&Asm[skg][m][0]) = *reinterpret_cast<const uint4*>(h);
    }
    // --- stage B: async global->LDS, pre-swizzled bf16; kg == pass (tid*16 < 4096) ---
    {
      char* bbase = (char*)&Bsm[0][0][0];
      const char* gbase = (const char*)w2p + ((size_t)(k0 >> 3)) * (LD_ * 8 * 2)
                          + (size_t)col0 * 16 + tid * 16;
#pragma unroll
      for (int p = 0; p < 4; ++p)
        async_copy16(bbase + p * 4096 + tid * 16, gbase + (size_t)p * (LD_ * 8 * 2));
    }
    __syncthreads();

    bf16x8 af[4], bfr[8];
#pragma unroll
    for (int i = 0; i < 4; ++i)
      af[i] = *reinterpret_cast<const bf16x8*>(&Asm[q][wm * 64 + i * 16 + c15][0]);
#pragma unroll
    for (int j = 0; j < 8; ++j)
      bfr[j] = *reinterpret_cast<const bf16x8*>(&Bsm[q][wn * 128 + j * 16 + c15][0]);
#pragma unroll
    for (int i = 0; i < 4; ++i)
#pragma unroll
      for (int j = 0; j < 8; ++j)
        acc[i][j] = __builtin_amdgcn_mfma_f32_16x16x32_bf16(af[i], bfr[j], acc[i][j], 0, 0, 0);
    __syncthreads();
  }

  // --- fused epilogue: tanh + V-dot + row reduction ---
  const int bb = row0 >> 11;   // batch index (2048 % 128 == 0, no straddle)
  float b2v[8], dwv[8], Vv[8];
#pragma unroll
  for (int j = 0; j < 8; ++j) {
    int n = col0 + wn * 128 + j * 16 + c15;
    b2v[j] = b2[n];
    dwv[j] = dec_w[bb * LD_ + n];
    Vv[j]  = V[n];
  }
#pragma unroll
  for (int i = 0; i < 4; ++i) {
#pragma unroll
    for (int r = 0; r < 4; ++r) {
      float v = 0.f;
#pragma unroll
      for (int j = 0; j < 8; ++j) {
        float e = acc[i][j][r] + b2v[j];          // enc_w + b2  (row=q*4+r, col=c15)
        v += tanhf(dwv[j] * e) * Vv[j];
      }
      v += __shfl_xor(v, 1);
      v += __shfl_xor(v, 2);
      v += __shfl_xor(v, 4);
      v += __shfl_xor(v, 8);                      // sum 16 cols within quad
      if (c15 == 0) {
        int row = row0 + wm * 64 + i * 16 + q * 4 + r;
        atomicAdd(&score[row], v);
      }
    }
  }
}

// softmax over T per batch; bV is softmax-invariant (scalar), omitted
__global__ void softmax_k(const float* __restrict__ score, float* __restrict__ attn) {
  int bb = blockIdx.x;
  int tid = threadIdx.x;
  int lane = tid & 63, wave = tid >> 6;
  __shared__ float red[4];
  float v[8];
  float mx = -3.4e38f;
#pragma unroll
  for (int i = 0; i < 8; ++i) {
    v[i] = score[bb * T_ + i * 256 + tid];
    mx = fmaxf(mx, v[i]);
  }
#pragma unroll
  for (int m = 32; m >= 1; m >>= 1) mx = fmaxf(mx, __shfl_xor(mx, m));
  if (lane == 0) red[wave] = mx;
  __syncthreads();
  mx = fmaxf(fmaxf(red[0], red[1]), fmaxf(red[2], red[3]));
  __syncthreads();
  float s = 0.f;
#pragma unroll
  for (int i = 0; i < 8; ++i) { v[i] = __expf(v[i] - mx); s += v[i]; }
#pragma unroll
  for (int m = 32; m >= 1; m >>= 1) s += __shfl_xor(s, m);
  if (lane == 0) red[wave] = s;
  __syncthreads();
  s = red[0] + red[1] + red[2] + red[3];
  float inv = 1.f / s;
#pragma unroll
  for (int i = 0; i < 8; ++i) attn[bb * T_ + i * 256 + tid] = v[i] * inv;
}

// context[b][h] = sum_t attn[b][t] * enc[b][t][h]; t split 4-way with atomics
__global__ void context_k(const float* __restrict__ enc, const float* __restrict__ attn,
                          float* __restrict__ ctx) {
  int bb = blockIdx.y;
  int hc = blockIdx.x & 3, tc = blockIdx.x >> 2;   // gridDim.x = 16
  int h = hc * 256 + threadIdx.x;
  __shared__ float sat[512];
  int t0 = tc * 512;
  for (int i = threadIdx.x; i < 512; i += 256) sat[i] = attn[bb * T_ + t0 + i];
  __syncthreads();
  const float* base = enc + ((size_t)bb * T_ + t0) * H_ + h;
  float a0 = 0.f, a1 = 0.f, a2 = 0.f, a3 = 0.f;
  for (int t = 0; t < 512; t += 4) {
    a0 += sat[t + 0] * base[(size_t)(t + 0) * H_];
    a1 += sat[t + 1] * base[(size_t)(t + 1) * H_];
    a2 += sat[t + 2] * base[(size_t)(t + 2) * H_];
    a3 += sat[t + 3] * base[(size_t)(t + 3) * H_];
  }
  atomicAdd(&ctx[bb * H_ + h], (a0 + a1) + (a2 + a3));
}

extern "C" void kernel_launch(void* const* d_in, const int* in_sizes, int n_in,
                              void* d_out, int out_size, void* d_ws, size_t ws_size,
                              hipStream_t stream) {
  const float* enc = (const float*)d_in[0];
  const float* dec = (const float*)d_in[1];
  const float* W1  = (const float*)d_in[2];
  const float* b1  = (const float*)d_in[3];
  const float* W2  = (const float*)d_in[4];
  const float* b2  = (const float*)d_in[5];
  const float* V   = (const float*)d_in[6];
  // d_in[7] = bV: softmax-invariant additive scalar -> ignored.

  char* ws = (char*)d_ws;
  __hip_bfloat16* w2p = (__hip_bfloat16*)ws;                       // 2 MB
  float* dec_w = (float*)(ws + (2u << 20));                        // 128 KB
  float* score = (float*)(ws + (2u << 20) + (128u << 10));         // 256 KB

  float* out  = (float*)d_out;
  float* ctx  = out;              // [B, H]   = 32768 floats
  float* attn = out + B_ * H_;    // [B, T, 1] = 65536 floats

  hipMemsetAsync(score, 0, (size_t)M_ * sizeof(float), stream);
  hipMemsetAsync(ctx, 0, (size_t)B_ * H_ * sizeof(float), stream);

  convert_w2<<<(H_ * LD_ / 8) / 256, 256, 0, stream>>>(W2, w2p);
  dec_proj<<<B_ * 4, 256, 0, stream>>>(dec, W1, b1, dec_w);
  score_gemm<<<dim3(LD_ / 256, M_ / 128), 256, 0, stream>>>(enc, w2p, dec_w, b2, V, score);
  softmax_k<<<B_, 256, 0, stream>>>(score, attn);
  context_k<<<dim3(16, B_), 256, 0, stream>>>(enc, attn, ctx);
}